// Round 14
// baseline (221.867 us; speedup 1.0000x reference)
//
#include <hip/hip_runtime.h>
#include <hip/hip_bf16.h>
#include <math.h>

// Problem constants
#define BB    8
#define HH    160
#define WW    256
#define CC    700
#define KK    250
#define NBINS 750
#define NHIST 30
#define NJIT  60
#define NFRM  90
#define PP    (HH*WW)      // 40960
#define TOUT  500
#define MAGIC (400.0f/750.0f)

// GEMM dims (fp8 path)
#define MPAD   512
#define NPAD   768
#define KPTOT  640         // K / 64  (ktpairs)
#define KSPLIT 32
#define KPZ    20          // ktpairs per z slice (1280 px)
#define BSCALE     64.0f
#define INV_BSCALE (1.0f/64.0f)
#define PA_BLKS (32*20)            // 640 A blocks (4 supertiles each)
#define PBD_BLKS ((768*640)/256)   // 1920 B-direct blocks (1 row-ktpair/thread)

typedef __attribute__((ext_vector_type(8))) short short8;
typedef __attribute__((ext_vector_type(4))) float f32x4;

// Software fallback f32 -> OCP e4m3fn (RNE, FTZ below 2^-6, clamp +-448)
__device__ __forceinline__ unsigned char f2fp8(float x) {
    x = fminf(fmaxf(x, -440.f), 440.f);
    unsigned u = __builtin_bit_cast(unsigned, x);
    unsigned s = (u >> 24) & 0x80u;
    int e = (u >> 23) & 0xFF;
    if (e < 121) return (unsigned char)s;
    unsigned u2 = u + 0x7FFFFu + ((u >> 20) & 1u);
    int e2 = (u2 >> 23) & 0xFF;
    unsigned m = (u2 >> 20) & 7u;
    if (e2 > 135 || (e2 == 135 && m == 7u)) return (unsigned char)(s | 0x7E);
    return (unsigned char)(s | ((unsigned)(e2 - 120) << 3) | m);
}

// 4 x f32 -> packed fp8x4 (HW converter when available)
__device__ __forceinline__ unsigned pk4_fp8(float a, float b, float c, float d) {
#if __has_builtin(__builtin_amdgcn_cvt_pk_fp8_f32)
    int v = __builtin_amdgcn_cvt_pk_fp8_f32(a, b, 0, false);
    v = __builtin_amdgcn_cvt_pk_fp8_f32(c, d, v, true);
    return (unsigned)v;
#else
    return (unsigned)f2fp8(a) | ((unsigned)f2fp8(b) << 8)
         | ((unsigned)f2fp8(c) << 16) | ((unsigned)f2fp8(d) << 24);
#endif
}

__device__ __forceinline__ void gload16(const void* g, void* l) {
    __builtin_amdgcn_global_load_lds(
        (const __attribute__((address_space(1))) unsigned int*)g,
        (__attribute__((address_space(3))) unsigned int*)l, 16, 0, 0);
}

// LDS byte-offset swizzle (involution; XORs bits 8-10 into bank bits 4-6)
__device__ __forceinline__ int SWZ(int X) { return X ^ (((X >> 8) & 7) << 4); }

// Fragment-ready fp8 layout, per 16-row tile and ktpair (64 px) 1KB block:
//   byte(r, pl) = (pl>>6)*1024 + (((pl>>3)&3)*16 + r)*16 + ((pl>>5)&1)*8 + (pl&7)
__device__ __forceinline__ int FRX(int r, int pl) {
    return ((pl >> 6) << 10) | ((((pl >> 3) & 3) * 16 + r) << 4)
         | (((pl >> 5) & 1) << 3) | (pl & 7);
}

// ---------------------------------------------------------------------------
// pack_ab: A via LDS transpose (aligned float4 loads, dx absorbed in LDS
// byte-scatter — r13-proven). B: LDS-FREE direct stream — for fixed (row r,
// ktpair kp), px {quad*8..+7} map to 8 CONTIGUOUS output bytes, so each
// thread converts 128 px and emits 8x dwordx2 at fragment addresses.
// No barriers, no readback on the B side.
// ---------------------------------------------------------------------------
__global__ __launch_bounds__(256) void pack_ab(
    const float* __restrict__ img, const int* __restrict__ eye,
    const float* __restrict__ filt,
    unsigned char* __restrict__ Ap, unsigned char* __restrict__ Bp)
{
    __shared__ unsigned char lds[8192];
    const int t = threadIdx.x, w = t >> 6, l = t & 63;
    const int bid = blockIdx.x;

    if (bid < PA_BLKS) {
        // ----- A: jittered image, 4 supertiles (16 rows x 512 px) -----
        const int mt = bid / 20, ch4 = bid % 20;
        int rbv[4], rdy[4], rdx[4]; bool rok[4];
        #pragma unroll
        for (int sub = 0; sub < 4; ++sub) {
            int r = sub*4 + w, m = mt*16 + r;
            rok[sub] = (m < 480);
            int b = 0, dy = 0, dx = 0;
            if (rok[sub]) {
                b = m / 60; int f = m % 60;
                dy = eye[(b*NJIT + f)*2 + 0];
                dx = eye[(b*NJIT + f)*2 + 1];
            }
            rbv[sub] = b; rdy[sub] = dy; rdx[sub] = dx;
        }
        for (int q = 0; q < 4; ++q) {
            const int ch = ch4*4 + q;
            const int kbase = ch * 512;
            #pragma unroll
            for (int sub = 0; sub < 4; ++sub) {
                const int r = sub*4 + w;
                const float* imgb = img + (size_t)rbv[sub]*PP;
                const int dx = rdx[sub];
                #pragma unroll
                for (int h = 0; h < 2; ++h) {
                    const int ir = (kbase >> 8) + h + rdy[sub];
                    const bool ok = rok[sub] && (ir < HH);
                    float4 v = make_float4(0.f,0.f,0.f,0.f);
                    if (ok) v = *(const float4*)(imgb + ir*WW + 4*l);  // aligned
                    unsigned pk = pk4_fp8(v.x, v.y, v.z, v.w);
                    const int plb = h*256;
                    if (!ok || l >= 60)
                        *(unsigned*)(lds + SWZ(FRX(r, plb + 4*l))) = 0u;
                    if (ok) {
                        #pragma unroll
                        for (int j = 0; j < 4; ++j) {
                            int pc = 4*l + j - dx;
                            if (pc >= 0)
                                lds[SWZ(FRX(r, plb + pc))] =
                                    (unsigned char)(pk >> (8*j));
                        }
                    }
                }
            }
            __syncthreads();
            unsigned char* outp = Ap + ((size_t)mt*KPTOT + ch*8)*1024;
            #pragma unroll
            for (int i = 0; i < 2; ++i) {
                int X = i*4096 + t*16;
                short8 v = *(const short8*)(lds + SWZ(X));
                *(short8*)(outp + X) = v;
            }
            __syncthreads();
        }
    } else {
        // ----- B direct: thread = (row r, ktpair kp), 64 px, no LDS -----
        const int tidg = (bid - PA_BLKS)*256 + t;
        const int kp = tidg % KPTOT;
        const int r  = tidg / KPTOT;            // 0..767
        const int nt = r >> 4, rloc = r & 15;
        const bool ok = (r < CC);
        const float* rp = filt + (size_t)(ok ? r : 0)*PP + kp*64;
        unsigned char* op = Bp + ((size_t)nt*KPTOT + kp)*1024 + rloc*16;
        #pragma unroll
        for (int hi = 0; hi < 2; ++hi) {
            float4 fv[8];
            #pragma unroll
            for (int qd = 0; qd < 8; ++qd)
                fv[qd] = ok ? *(const float4*)(rp + hi*32 + qd*4)
                            : make_float4(0.f,0.f,0.f,0.f);
            #pragma unroll
            for (int quad = 0; quad < 4; ++quad) {
                float4 a = fv[quad*2], b2 = fv[quad*2+1];
                uint2 dv;
                dv.x = pk4_fp8(a.x*BSCALE,  a.y*BSCALE,  a.z*BSCALE,  a.w*BSCALE);
                dv.y = pk4_fp8(b2.x*BSCALE, b2.y*BSCALE, b2.z*BSCALE, b2.w*BSCALE);
                *(uint2*)(op + quad*256 + hi*8) = dv;
            }
        }
    }
}

// ---------------------------------------------------------------------------
// gemm_f8: C += A x B in fp8 (e4m3), MFMA 16x16x32_fp8_fp8.
// BM=BN=128, BK=64. 4 waves (2x2), wave = 64x64 (acc[4][4]).
// 768 blocks; bijective XCD swizzle: all 24 blocks of a z-slice land on
// XCD z&7 -> operand re-reads become in-XCD L2 hits.
// ---------------------------------------------------------------------------
__global__ __launch_bounds__(256) void gemm_f8(
    const unsigned char* __restrict__ Ap, const unsigned char* __restrict__ Bp,
    __hip_bfloat16* __restrict__ part)
{
    __shared__ unsigned char As[8192];
    __shared__ unsigned char Bs[8192];

    const int t = threadIdx.x, l = t & 63, w = t >> 6;
    const int bid = blockIdx.x;
    const int g   = bid >> 3;
    const int z   = (bid & 7) + 8*(g / 24);
    const int tt  = g % 24;
    const int mtile = tt / 6, ntile = tt % 6;
    const int wr = w >> 1, wc = w & 1;

    f32x4 acc[4][4] = {};

    for (int step = 0; step < KPZ; ++step) {
        const size_t kp = (size_t)z*KPZ + step;
        const int tb0 = w*2, tb1 = w*2 + 1;
        gload16(Ap + ((size_t)(mtile*8 + tb0)*KPTOT + kp)*1024 + l*16, As + tb0*1024);
        gload16(Ap + ((size_t)(mtile*8 + tb1)*KPTOT + kp)*1024 + l*16, As + tb1*1024);
        gload16(Bp + ((size_t)(ntile*8 + tb0)*KPTOT + kp)*1024 + l*16, Bs + tb0*1024);
        gload16(Bp + ((size_t)(ntile*8 + tb1)*KPTOT + kp)*1024 + l*16, Bs + tb1*1024);
        __syncthreads();

        ulonglong2 a[4], b[4];
        #pragma unroll
        for (int i = 0; i < 4; ++i)
            a[i] = *(const ulonglong2*)(As + (wr*4 + i)*1024 + l*16);
        #pragma unroll
        for (int j = 0; j < 4; ++j)
            b[j] = *(const ulonglong2*)(Bs + (wc*4 + j)*1024 + l*16);
        #pragma unroll
        for (int i = 0; i < 4; ++i)
            #pragma unroll
            for (int j = 0; j < 4; ++j) {
                acc[i][j] = __builtin_amdgcn_mfma_f32_16x16x32_fp8_fp8(
                    (long long)a[i].x, (long long)b[j].x, acc[i][j], 0, 0, 0);
                acc[i][j] = __builtin_amdgcn_mfma_f32_16x16x32_fp8_fp8(
                    (long long)a[i].y, (long long)b[j].y, acc[i][j], 0, 0, 0);
            }
        __syncthreads();
    }

    const int rbase = (l >> 4)*4, cl = l & 15;
    #pragma unroll
    for (int i = 0; i < 4; ++i)
        #pragma unroll
        for (int j = 0; j < 4; ++j) {
            int m = mtile*128 + wr*64 + i*16 + rbase;
            int n = ntile*128 + wc*64 + j*16 + cl;
            __hip_bfloat16* p = part + ((size_t)z*MPAD + m)*NPAD + n;
            #pragma unroll
            for (int r = 0; r < 4; ++r)
                p[(size_t)r*NPAD] = __float2bfloat16(acc[i][j][r]);
        }
}

// ---------------------------------------------------------------------------
// build_spat: spatT[b][c][fr] = history | (sum of bf16 partials) / BSCALE
// Reads stay coalesced; writes are transposed scattered 4B (posted).
// ---------------------------------------------------------------------------
__global__ __launch_bounds__(256) void build_spat(
    const float* __restrict__ hist, const __hip_bfloat16* __restrict__ part,
    float* __restrict__ spatT)
{
    int idx = blockIdx.x*256 + threadIdx.x;
    if (idx >= BB*NFRM*CC) return;
    int c   = idx % CC;
    int rem = idx / CC;
    int fr  = rem % NFRM;
    int b   = rem / NFRM;
    float v;
    if (fr < NHIST) {
        v = hist[(b*NHIST + fr)*CC + c];
    } else {
        int m = b*NJIT + (fr - NHIST);
        v = 0.f;
        #pragma unroll
        for (int kp = 0; kp < KSPLIT; ++kp)
            v += __bfloat162float(part[((size_t)kp*MPAD + m)*NPAD + c]);
        v *= INV_BSCALE;
    }
    spatT[((size_t)b*CC + c)*NFRM + fr] = v;
}

// ---------------------------------------------------------------------------
// conv_loss: stage the (b,c) spat column (90 floats, contiguous in spatT)
// into LDS, gather/upsample from LDS, depthwise conv, loss partial.
// ---------------------------------------------------------------------------
__global__ __launch_bounds__(64) void conv_loss(
    const float* __restrict__ spatT, const int* __restrict__ sel,
    const float* __restrict__ wts,  const float* __restrict__ tc,
    const float* __restrict__ fb,   const float* __restrict__ spk,
    const float* __restrict__ tmask, float* __restrict__ lpart)
{
    __shared__ float tcs[256];
    __shared__ float spc[96];
    __shared__ float ups[864];

    const int lane = threadIdx.x;
    const int c = blockIdx.x;
    const int b = blockIdx.y;

    for (int k = lane; k < 256; k += 64)
        tcs[k] = (k < KK) ? tc[c*KK + k] : 0.f;
    {
        const float* spT = spatT + (size_t)(b*CC + c)*NFRM;
        for (int i = lane; i < NFRM; i += 64) spc[i] = spT[i];
    }
    __syncthreads();

    for (int tt = lane; tt < 768; tt += 64) {
        float v = 0.f;
        if (tt < NBINS) {
            int base = (b*NBINS + tt);
            int2   s2 = *(const int2*)  (sel + base*2);
            float2 w2 = *(const float2*)(wts + base*2);
            v = w2.x * spc[s2.x] + w2.y * spc[s2.y];
        }
        ups[tt + (tt >> 3)] = v;
    }
    __syncthreads();

    const int t0 = lane * 8;
    float u[16];
    #pragma unroll
    for (int j = 0; j < 16; ++j) { int q = t0 + j; u[j] = ups[q + (q >> 3)]; }

    float acc[8] = {};
    #pragma unroll 4
    for (int kc = 0; kc < 248; kc += 8) {
        #pragma unroll
        for (int kk = 0; kk < 8; ++kk) {
            float w2 = tcs[kc + kk];
            #pragma unroll
            for (int j = 0; j < 8; ++j) acc[j] += w2 * u[kk + j];
        }
        #pragma unroll
        for (int j = 0; j < 8; ++j) u[j] = u[j + 8];
        #pragma unroll
        for (int j = 0; j < 8; ++j) {
            int q = t0 + kc + 16 + j;
            u[j + 8] = ups[q + (q >> 3)];
        }
    }
    #pragma unroll
    for (int kk = 0; kk < 8; ++kk) {
        float w2 = tcs[248 + kk];
        #pragma unroll
        for (int j = 0; j < 8; ++j) acc[j] += w2 * u[kk + j];
    }

    const size_t bc = (size_t)b*CC + c;
    const float* fbp = fb  + bc*(TOUT+1);
    const float* sp  = spk + bc*NBINS + KK;
    const float* tm  = tmask + (size_t)b*TOUT;
    float lsum = 0.f;
    #pragma unroll
    for (int j = 0; j < 8; ++j) {
        int tt = t0 + j;
        if (tt < TOUT) {
            float g  = acc[j] + fbp[tt];
            float sv = sp[tt];
            lsum += (__expf(g) - sv*g) * tm[tt];
        }
    }
    #pragma unroll
    for (int off = 32; off > 0; off >>= 1)
        lsum += __shfl_down(lsum, off);
    if (lane == 0) lpart[bc] = lsum * MAGIC;
}

__global__ __launch_bounds__(256) void reduce_out(
    const float* __restrict__ lpart, float* __restrict__ out)
{
    __shared__ float red[256];
    int b = blockIdx.x, t = threadIdx.x;
    float s = 0.f;
    for (int i = t; i < CC; i += 256) s += lpart[(size_t)b*CC + i];
    red[t] = s; __syncthreads();
    for (int o = 128; o > 0; o >>= 1) {
        if (t < o) red[t] += red[t+o];
        __syncthreads();
    }
    if (t == 0) out[b] = red[0];
}

extern "C" void kernel_launch(void* const* d_in, const int* in_sizes, int n_in,
                              void* d_out, int out_size, void* d_ws, size_t ws_size,
                              hipStream_t stream) {
    const float* image = (const float*)d_in[0];
    const float* spk   = (const float*)d_in[1];
    const int*   eye   = (const int*)d_in[2];
    const float* tmask = (const float*)d_in[3];
    const int*   sel   = (const int*)d_in[4];
    const float* wts   = (const float*)d_in[5];
    const float* filt  = (const float*)d_in[6];
    const float* tc    = (const float*)d_in[7];
    const float* fb    = (const float*)d_in[8];
    const float* hist  = (const float*)d_in[9];
    float* out = (float*)d_out;

    unsigned char* Ap = (unsigned char*)d_ws;                     // 20.97 MB fp8
    unsigned char* Bp = Ap + (size_t)32*KPTOT*1024;               // 31.46 MB fp8
    __hip_bfloat16* part = (__hip_bfloat16*)(Bp + (size_t)48*KPTOT*1024); // 25.2 MB
    float* spatT = (float*)(part + (size_t)KSPLIT*MPAD*NPAD);     // 2.0 MB
    float* lpart = spatT + (size_t)BB*NFRM*CC;

    pack_ab  <<<dim3(PA_BLKS + PBD_BLKS), 256, 0, stream>>>(image, eye, filt, Ap, Bp);
    gemm_f8  <<<dim3(8*96), 256, 0, stream>>>(Ap, Bp, part);
    build_spat<<<dim3((BB*NFRM*CC + 255)/256), 256, 0, stream>>>(hist, part, spatT);
    conv_loss<<<dim3(CC, BB), 64, 0, stream>>>(spatT, sel, wts, tc, fb, spk, tmask, lpart);
    reduce_out<<<dim3(BB), 256, 0, stream>>>(lpart, out);
}

// Round 15
// 103.902 us; speedup vs baseline: 2.1353x; 2.1353x over previous
//
#include <hip/hip_runtime.h>
#include <hip/hip_bf16.h>
#include <math.h>

// Problem constants
#define BB    8
#define HH    160
#define WW    256
#define CC    700
#define KK    250
#define NBINS 750
#define NHIST 30
#define NJIT  60
#define NFRM  90
#define PP    (HH*WW)      // 40960
#define TOUT  500
#define MAGIC (400.0f/750.0f)

// GEMM dims (fp8 path)
#define MPAD   512
#define NPAD   768
#define KPTOT  640         // K / 64  (ktpairs)
#define KSPLIT 32
#define KPZ    20          // ktpairs per z slice (1280 px)
#define BSCALE     64.0f
#define INV_BSCALE (1.0f/64.0f)
#define PA_BLKS (32*20)    // 640  A blocks (4 supertiles each)
#define PB_BLKS (48*20)    // 960  B blocks (4 supertiles each)

typedef __attribute__((ext_vector_type(8))) short short8;
typedef __attribute__((ext_vector_type(4))) float f32x4;

// Software fallback f32 -> OCP e4m3fn (RNE, FTZ below 2^-6, clamp +-448)
__device__ __forceinline__ unsigned char f2fp8(float x) {
    x = fminf(fmaxf(x, -440.f), 440.f);
    unsigned u = __builtin_bit_cast(unsigned, x);
    unsigned s = (u >> 24) & 0x80u;
    int e = (u >> 23) & 0xFF;
    if (e < 121) return (unsigned char)s;
    unsigned u2 = u + 0x7FFFFu + ((u >> 20) & 1u);
    int e2 = (u2 >> 23) & 0xFF;
    unsigned m = (u2 >> 20) & 7u;
    if (e2 > 135 || (e2 == 135 && m == 7u)) return (unsigned char)(s | 0x7E);
    return (unsigned char)(s | ((unsigned)(e2 - 120) << 3) | m);
}

// 4 x f32 -> packed fp8x4 (HW converter when available)
__device__ __forceinline__ unsigned pk4_fp8(float a, float b, float c, float d) {
#if __has_builtin(__builtin_amdgcn_cvt_pk_fp8_f32)
    int v = __builtin_amdgcn_cvt_pk_fp8_f32(a, b, 0, false);
    v = __builtin_amdgcn_cvt_pk_fp8_f32(c, d, v, true);
    return (unsigned)v;
#else
    return (unsigned)f2fp8(a) | ((unsigned)f2fp8(b) << 8)
         | ((unsigned)f2fp8(c) << 16) | ((unsigned)f2fp8(d) << 24);
#endif
}

__device__ __forceinline__ void gload16(const void* g, void* l) {
    __builtin_amdgcn_global_load_lds(
        (const __attribute__((address_space(1))) unsigned int*)g,
        (__attribute__((address_space(3))) unsigned int*)l, 16, 0, 0);
}

// LDS byte-offset swizzle (involution; XORs bits 8-10 into bank bits 4-6)
__device__ __forceinline__ int SWZ(int X) { return X ^ (((X >> 8) & 7) << 4); }

// Fragment-ready fp8 layout, per 16-row tile and ktpair (64 px) 1KB block:
//   byte(r, pl) = (pl>>6)*1024 + (((pl>>3)&3)*16 + r)*16 + ((pl>>5)&1)*8 + (pl&7)
__device__ __forceinline__ int FRX(int r, int pl) {
    return ((pl >> 6) << 10) | ((((pl >> 3) & 3) * 16 + r) << 4)
         | (((pl >> 5) & 1) << 3) | (pl & 7);
}

// ---------------------------------------------------------------------------
// pack_ab (r13-proven): A via LDS transpose with ALIGNED float4 loads (dx
// absorbed in LDS byte-scatter). B via coalesced float4 (one contiguous 1KB
// wave-load per row) -> LDS frag layout -> contiguous 1KB wave-stores.
// Wave-level contiguity is the invariant that matters.
// ---------------------------------------------------------------------------
__global__ __launch_bounds__(256) void pack_ab(
    const float* __restrict__ img, const int* __restrict__ eye,
    const float* __restrict__ filt,
    unsigned char* __restrict__ Ap, unsigned char* __restrict__ Bp)
{
    __shared__ unsigned char lds[8192];
    const int t = threadIdx.x, w = t >> 6, l = t & 63;
    const int bid = blockIdx.x;

    if (bid < PA_BLKS) {
        // ----- A: jittered image, 4 supertiles (16 rows x 512 px) -----
        const int mt = bid / 20, ch4 = bid % 20;
        int rbv[4], rdy[4], rdx[4]; bool rok[4];
        #pragma unroll
        for (int sub = 0; sub < 4; ++sub) {
            int r = sub*4 + w, m = mt*16 + r;
            rok[sub] = (m < 480);
            int b = 0, dy = 0, dx = 0;
            if (rok[sub]) {
                b = m / 60; int f = m % 60;
                dy = eye[(b*NJIT + f)*2 + 0];
                dx = eye[(b*NJIT + f)*2 + 1];
            }
            rbv[sub] = b; rdy[sub] = dy; rdx[sub] = dx;
        }
        for (int q = 0; q < 4; ++q) {
            const int ch = ch4*4 + q;
            const int kbase = ch * 512;
            #pragma unroll
            for (int sub = 0; sub < 4; ++sub) {
                const int r = sub*4 + w;
                const float* imgb = img + (size_t)rbv[sub]*PP;
                const int dx = rdx[sub];
                #pragma unroll
                for (int h = 0; h < 2; ++h) {
                    const int ir = (kbase >> 8) + h + rdy[sub];
                    const bool ok = rok[sub] && (ir < HH);
                    float4 v = make_float4(0.f,0.f,0.f,0.f);
                    if (ok) v = *(const float4*)(imgb + ir*WW + 4*l);  // aligned
                    unsigned pk = pk4_fp8(v.x, v.y, v.z, v.w);
                    const int plb = h*256;
                    // zero tail / invalid rows first; same-wave LDS ops are
                    // program-ordered so data bytes overwrite where valid.
                    if (!ok || l >= 60)
                        *(unsigned*)(lds + SWZ(FRX(r, plb + 4*l))) = 0u;
                    if (ok) {
                        #pragma unroll
                        for (int j = 0; j < 4; ++j) {
                            int pc = 4*l + j - dx;
                            if (pc >= 0)
                                lds[SWZ(FRX(r, plb + pc))] =
                                    (unsigned char)(pk >> (8*j));
                        }
                    }
                }
            }
            __syncthreads();
            unsigned char* outp = Ap + ((size_t)mt*KPTOT + ch*8)*1024;
            #pragma unroll
            for (int i = 0; i < 2; ++i) {
                int X = i*4096 + t*16;
                short8 v = *(const short8*)(lds + SWZ(X));
                *(short8*)(outp + X) = v;
            }
            __syncthreads();
        }
    } else {
        // ----- B: filters x BSCALE, 4 supertiles, coalesced wave rows -----
        const int bb = bid - PA_BLKS;
        const int nt = bb / 20, ch4 = bb % 20;
        for (int q = 0; q < 4; ++q) {
            const int ch = ch4*4 + q;
            const int kbase = ch * 512;
            #pragma unroll
            for (int sub = 0; sub < 4; ++sub) {
                int r = sub*4 + w, n = nt*16 + r;
                float4 va = make_float4(0.f,0.f,0.f,0.f), vb = va;
                if (n < CC) {
                    const float* rowp = filt + (size_t)n*PP + kbase;
                    va = *(const float4*)(rowp + l*4);
                    vb = *(const float4*)(rowp + l*4 + 256);
                }
                unsigned da = pk4_fp8(va.x*BSCALE, va.y*BSCALE, va.z*BSCALE, va.w*BSCALE);
                unsigned db = pk4_fp8(vb.x*BSCALE, vb.y*BSCALE, vb.z*BSCALE, vb.w*BSCALE);
                int Xa = FRX(r, 4*l);
                *(unsigned*)(lds + SWZ(Xa)) = da;
                *(unsigned*)(lds + SWZ(Xa + (4 << 10))) = db;
            }
            __syncthreads();
            unsigned char* outp = Bp + ((size_t)nt*KPTOT + ch*8)*1024;
            #pragma unroll
            for (int i = 0; i < 2; ++i) {
                int X = i*4096 + t*16;
                short8 v = *(const short8*)(lds + SWZ(X));
                *(short8*)(outp + X) = v;
            }
            __syncthreads();
        }
    }
}

// ---------------------------------------------------------------------------
// gemm_f8: C += A x B in fp8 (e4m3), MFMA 16x16x32_fp8_fp8.
// BM=BN=128, BK=64. 4 waves (2x2), wave = 64x64 (acc[4][4]).
// 768 blocks; bijective XCD swizzle: all 24 blocks of a z-slice land on
// XCD z&7 -> operand re-reads become in-XCD L2 hits.
// ---------------------------------------------------------------------------
__global__ __launch_bounds__(256) void gemm_f8(
    const unsigned char* __restrict__ Ap, const unsigned char* __restrict__ Bp,
    __hip_bfloat16* __restrict__ part)
{
    __shared__ unsigned char As[8192];
    __shared__ unsigned char Bs[8192];

    const int t = threadIdx.x, l = t & 63, w = t >> 6;
    const int bid = blockIdx.x;
    const int g   = bid >> 3;
    const int z   = (bid & 7) + 8*(g / 24);
    const int tt  = g % 24;
    const int mtile = tt / 6, ntile = tt % 6;
    const int wr = w >> 1, wc = w & 1;

    f32x4 acc[4][4] = {};

    for (int step = 0; step < KPZ; ++step) {
        const size_t kp = (size_t)z*KPZ + step;
        const int tb0 = w*2, tb1 = w*2 + 1;
        gload16(Ap + ((size_t)(mtile*8 + tb0)*KPTOT + kp)*1024 + l*16, As + tb0*1024);
        gload16(Ap + ((size_t)(mtile*8 + tb1)*KPTOT + kp)*1024 + l*16, As + tb1*1024);
        gload16(Bp + ((size_t)(ntile*8 + tb0)*KPTOT + kp)*1024 + l*16, Bs + tb0*1024);
        gload16(Bp + ((size_t)(ntile*8 + tb1)*KPTOT + kp)*1024 + l*16, Bs + tb1*1024);
        __syncthreads();

        ulonglong2 a[4], b[4];
        #pragma unroll
        for (int i = 0; i < 4; ++i)
            a[i] = *(const ulonglong2*)(As + (wr*4 + i)*1024 + l*16);
        #pragma unroll
        for (int j = 0; j < 4; ++j)
            b[j] = *(const ulonglong2*)(Bs + (wc*4 + j)*1024 + l*16);
        #pragma unroll
        for (int i = 0; i < 4; ++i)
            #pragma unroll
            for (int j = 0; j < 4; ++j) {
                acc[i][j] = __builtin_amdgcn_mfma_f32_16x16x32_fp8_fp8(
                    (long long)a[i].x, (long long)b[j].x, acc[i][j], 0, 0, 0);
                acc[i][j] = __builtin_amdgcn_mfma_f32_16x16x32_fp8_fp8(
                    (long long)a[i].y, (long long)b[j].y, acc[i][j], 0, 0, 0);
            }
        __syncthreads();
    }

    const int rbase = (l >> 4)*4, cl = l & 15;
    #pragma unroll
    for (int i = 0; i < 4; ++i)
        #pragma unroll
        for (int j = 0; j < 4; ++j) {
            int m = mtile*128 + wr*64 + i*16 + rbase;
            int n = ntile*128 + wc*64 + j*16 + cl;
            __hip_bfloat16* p = part + ((size_t)z*MPAD + m)*NPAD + n;
            #pragma unroll
            for (int r = 0; r < 4; ++r)
                p[(size_t)r*NPAD] = __float2bfloat16(acc[i][j][r]);
        }
}

// ---------------------------------------------------------------------------
// build_spat: spatT[b][c][fr] = history | (sum of bf16 partials) / BSCALE
// Reads coalesced; transposed scattered 4B writes (posted).
// ---------------------------------------------------------------------------
__global__ __launch_bounds__(256) void build_spat(
    const float* __restrict__ hist, const __hip_bfloat16* __restrict__ part,
    float* __restrict__ spatT)
{
    int idx = blockIdx.x*256 + threadIdx.x;
    if (idx >= BB*NFRM*CC) return;
    int c   = idx % CC;
    int rem = idx / CC;
    int fr  = rem % NFRM;
    int b   = rem / NFRM;
    float v;
    if (fr < NHIST) {
        v = hist[(b*NHIST + fr)*CC + c];
    } else {
        int m = b*NJIT + (fr - NHIST);
        v = 0.f;
        #pragma unroll
        for (int kp = 0; kp < KSPLIT; ++kp)
            v += __bfloat162float(part[((size_t)kp*MPAD + m)*NPAD + c]);
        v *= INV_BSCALE;
    }
    spatT[((size_t)b*CC + c)*NFRM + fr] = v;
}

// ---------------------------------------------------------------------------
// conv_loss: stage the (b,c) spat column (90 floats, contiguous in spatT)
// into LDS, gather/upsample from LDS, depthwise conv, loss partial.
// ---------------------------------------------------------------------------
__global__ __launch_bounds__(64) void conv_loss(
    const float* __restrict__ spatT, const int* __restrict__ sel,
    const float* __restrict__ wts,  const float* __restrict__ tc,
    const float* __restrict__ fb,   const float* __restrict__ spk,
    const float* __restrict__ tmask, float* __restrict__ lpart)
{
    __shared__ float tcs[256];
    __shared__ float spc[96];
    __shared__ float ups[864];

    const int lane = threadIdx.x;
    const int c = blockIdx.x;
    const int b = blockIdx.y;

    for (int k = lane; k < 256; k += 64)
        tcs[k] = (k < KK) ? tc[c*KK + k] : 0.f;
    {
        const float* spT = spatT + (size_t)(b*CC + c)*NFRM;
        for (int i = lane; i < NFRM; i += 64) spc[i] = spT[i];
    }
    __syncthreads();

    for (int tt = lane; tt < 768; tt += 64) {
        float v = 0.f;
        if (tt < NBINS) {
            int base = (b*NBINS + tt);
            int2   s2 = *(const int2*)  (sel + base*2);
            float2 w2 = *(const float2*)(wts + base*2);
            v = w2.x * spc[s2.x] + w2.y * spc[s2.y];
        }
        ups[tt + (tt >> 3)] = v;
    }
    __syncthreads();

    const int t0 = lane * 8;
    float u[16];
    #pragma unroll
    for (int j = 0; j < 16; ++j) { int q = t0 + j; u[j] = ups[q + (q >> 3)]; }

    float acc[8] = {};
    #pragma unroll 4
    for (int kc = 0; kc < 248; kc += 8) {
        #pragma unroll
        for (int kk = 0; kk < 8; ++kk) {
            float w2 = tcs[kc + kk];
            #pragma unroll
            for (int j = 0; j < 8; ++j) acc[j] += w2 * u[kk + j];
        }
        #pragma unroll
        for (int j = 0; j < 8; ++j) u[j] = u[j + 8];
        #pragma unroll
        for (int j = 0; j < 8; ++j) {
            int q = t0 + kc + 16 + j;
            u[j + 8] = ups[q + (q >> 3)];
        }
    }
    #pragma unroll
    for (int kk = 0; kk < 8; ++kk) {
        float w2 = tcs[248 + kk];
        #pragma unroll
        for (int j = 0; j < 8; ++j) acc[j] += w2 * u[kk + j];
    }

    const size_t bc = (size_t)b*CC + c;
    const float* fbp = fb  + bc*(TOUT+1);
    const float* sp  = spk + bc*NBINS + KK;
    const float* tm  = tmask + (size_t)b*TOUT;
    float lsum = 0.f;
    #pragma unroll
    for (int j = 0; j < 8; ++j) {
        int tt = t0 + j;
        if (tt < TOUT) {
            float g  = acc[j] + fbp[tt];
            float sv = sp[tt];
            lsum += (__expf(g) - sv*g) * tm[tt];
        }
    }
    #pragma unroll
    for (int off = 32; off > 0; off >>= 1)
        lsum += __shfl_down(lsum, off);
    if (lane == 0) lpart[bc] = lsum * MAGIC;
}

__global__ __launch_bounds__(256) void reduce_out(
    const float* __restrict__ lpart, float* __restrict__ out)
{
    __shared__ float red[256];
    int b = blockIdx.x, t = threadIdx.x;
    float s = 0.f;
    for (int i = t; i < CC; i += 256) s += lpart[(size_t)b*CC + i];
    red[t] = s; __syncthreads();
    for (int o = 128; o > 0; o >>= 1) {
        if (t < o) red[t] += red[t+o];
        __syncthreads();
    }
    if (t == 0) out[b] = red[0];
}

extern "C" void kernel_launch(void* const* d_in, const int* in_sizes, int n_in,
                              void* d_out, int out_size, void* d_ws, size_t ws_size,
                              hipStream_t stream) {
    const float* image = (const float*)d_in[0];
    const float* spk   = (const float*)d_in[1];
    const int*   eye   = (const int*)d_in[2];
    const float* tmask = (const float*)d_in[3];
    const int*   sel   = (const int*)d_in[4];
    const float* wts   = (const float*)d_in[5];
    const float* filt  = (const float*)d_in[6];
    const float* tc    = (const float*)d_in[7];
    const float* fb    = (const float*)d_in[8];
    const float* hist  = (const float*)d_in[9];
    float* out = (float*)d_out;

    unsigned char* Ap = (unsigned char*)d_ws;                     // 20.97 MB fp8
    unsigned char* Bp = Ap + (size_t)32*KPTOT*1024;               // 31.46 MB fp8
    __hip_bfloat16* part = (__hip_bfloat16*)(Bp + (size_t)48*KPTOT*1024); // 25.2 MB
    float* spatT = (float*)(part + (size_t)KSPLIT*MPAD*NPAD);     // 2.0 MB
    float* lpart = spatT + (size_t)BB*NFRM*CC;

    pack_ab  <<<dim3(PA_BLKS + PB_BLKS), 256, 0, stream>>>(image, eye, filt, Ap, Bp);
    gemm_f8  <<<dim3(8*96), 256, 0, stream>>>(Ap, Bp, part);
    build_spat<<<dim3((BB*NFRM*CC + 255)/256), 256, 0, stream>>>(hist, part, spatT);
    conv_loss<<<dim3(CC, BB), 64, 0, stream>>>(spatT, sel, wts, tc, fb, spk, tmask, lpart);
    reduce_out<<<dim3(BB), 256, 0, stream>>>(lpart, out);
}